// Round 8
// baseline (1617.889 us; speedup 1.0000x reference)
//
#include <hip/hip_runtime.h>
#include <math.h>

namespace {
constexpr int NB   = 256;          // graphs
constexpr int EPG  = 8192;         // edges per graph
constexpr int ETOT = NB * EPG;     // 2,097,152
constexpr int FH   = 64;           // hidden dim
constexpr int NN0  = NB * 512;     // 131072 nodes at full size
}

// ---- scratch (device globals: write-before-read each call, deterministic) ----
__device__ float g_feat[3][(size_t)NN0 * FH];   // rotating node-feature buffers
__device__ float g_xs[NB * 6 * FH];             // jumping-knowledge concat
__device__ int   g_esrc[2][ETOT];               // compacted edges (stage 0/1)
__device__ int   g_edst[2][ETOT];
__device__ int   g_ecnt[2][NB];

// ============================================================================
// Dual matmul: zr = x@Wr ; xl = x@Wl + b   (x: [M,K], W: [K,64], M % 128 == 0)
// v3: global_load_lds staging (HBM->LDS direct), unrolled k4 loop.
// ============================================================================
template<int K>
__global__ __launch_bounds__(256)
void mm_dual(const float* __restrict__ xext, int in_idx,
             const float* __restrict__ Wr, const float* __restrict__ Wl,
             const float* __restrict__ bias, int zr_idx, int xl_idx)
{
  constexpr int RPB = 128;          // rows per block
  constexpr int KC  = 32;           // k-chunk staged in LDS
  __shared__ float xs[RPB][KC];     // 16 KB
  const float* __restrict__ x = (in_idx < 0) ? xext : g_feat[in_idx];
  float* __restrict__ zr = g_feat[zr_idx];
  float* __restrict__ xl = g_feat[xl_idx];
  const int t = threadIdx.x;
  const int rowbase = blockIdx.x * RPB;
  const int f  = t & 31;            // this thread's column pair: f, f+32
  const int rg = t >> 5;            // 8 row-groups x 16 rows
  const int wv = t >> 6;            // wave id (0..3)
  float ar0[16], ar1[16], al0[16], al1[16];
  #pragma unroll
  for (int r = 0; r < 16; ++r) { ar0[r]=0.f; ar1[r]=0.f; al0[r]=0.f; al1[r]=0.f; }

  for (int c = 0; c < K / KC; ++c) {
    __syncthreads();                       // WAR: previous chunk fully consumed
    #pragma unroll
    for (int i = 0; i < 4; ++i) {          // 1024 lanes-slots of 16B = 16 KB
      const int idx = t + i * 256;
      const int r = idx >> 3, q = idx & 7;
      const float* gp = &x[(size_t)(rowbase + r) * K + c * KC + q * 4];
      // LDS dest: wave-uniform base + lane*16 (linear in lane order)
      float* lp = &xs[0][0] + (size_t)(i * 256 + wv * 64) * 4;
      __builtin_amdgcn_global_load_lds(
          (const __attribute__((address_space(1))) unsigned int*)gp,
          (__attribute__((address_space(3))) unsigned int*)lp, 16, 0, 0);
    }
    __syncthreads();                       // drains vmcnt: LDS writes visible
    #pragma unroll
    for (int k4 = 0; k4 < KC / 4; ++k4) {
      const int kb = c * KC + k4 * 4;
      const float* wrp = &Wr[kb * 64];
      const float* wlp = &Wl[kb * 64];
      const float wr00=wrp[f],    wr01=wrp[64+f],    wr02=wrp[128+f],    wr03=wrp[192+f];
      const float wr10=wrp[f+32], wr11=wrp[96+f],    wr12=wrp[160+f],    wr13=wrp[224+f];
      const float wl00=wlp[f],    wl01=wlp[64+f],    wl02=wlp[128+f],    wl03=wlp[192+f];
      const float wl10=wlp[f+32], wl11=wlp[96+f],    wl12=wlp[160+f],    wl13=wlp[224+f];
      #pragma unroll
      for (int r = 0; r < 16; ++r) {
        const float4 xv = *reinterpret_cast<const float4*>(&xs[rg*16 + r][k4*4]);
        ar0[r] += xv.x*wr00 + xv.y*wr01 + xv.z*wr02 + xv.w*wr03;
        ar1[r] += xv.x*wr10 + xv.y*wr11 + xv.z*wr12 + xv.w*wr13;
        al0[r] += xv.x*wl00 + xv.y*wl01 + xv.z*wl02 + xv.w*wl03;
        al1[r] += xv.x*wl10 + xv.y*wl11 + xv.z*wl12 + xv.w*wl13;
      }
    }
  }
  const float bv0 = bias[f], bv1 = bias[f + 32];
  #pragma unroll
  for (int r = 0; r < 16; ++r) {
    const size_t row = (size_t)(rowbase + rg * 16 + r);
    zr[row * 64 + f]      = ar0[r];
    zr[row * 64 + f + 32] = ar1[r];
    xl[row * 64 + f]      = al0[r] + bv0;
    xl[row * 64 + f + 32] = al1[r] + bv1;
  }
}

// ============================================================================
// Full-size (n=512/graph) mean-aggregation + residual + relu + fused gmp.
// v3: gather unrolled x4 with independent accumulators (hide L2 latency).
// ============================================================================
__global__ __launch_bounds__(1024)
void agg_full(int zr_idx, int xl_idx,
              const int* __restrict__ esrc, const int* __restrict__ edst,
              int out_idx, int xs_off)
{
  __shared__ unsigned int hist[512], bufA[512], bufB[512];
  __shared__ unsigned short csr[EPG];
  __shared__ float red[16][64];
  const float* __restrict__ zr  = g_feat[zr_idx];
  const float* __restrict__ xlb = g_feat[xl_idx];
  float* __restrict__ xout = g_feat[out_idx];
  const int g = blockIdx.x, t = threadIdx.x;
  const int gbase = g * 512, ebase = g * EPG;
  for (int i = t; i < 512; i += 1024) hist[i] = 0;
  __syncthreads();
  for (int e = t; e < EPG; e += 1024)
    atomicAdd(&hist[edst[ebase + e] - gbase], 1u);
  __syncthreads();
  if (t < 512) bufA[t] = hist[t];
  __syncthreads();
  unsigned int *pa = bufA, *pb = bufB;
  for (int off = 1; off < 512; off <<= 1) {      // Hillis-Steele inclusive scan
    if (t < 512) {
      unsigned int v = pa[t];
      if (t >= off) v += pa[t - off];
      pb[t] = v;
    }
    __syncthreads();
    unsigned int* tmp = pa; pa = pb; pb = tmp;
  }
  unsigned int excl = 0;
  if (t < 512) excl = pa[t] - hist[t];
  __syncthreads();
  if (t < 512) { bufA[t] = excl; bufB[t] = excl; }  // bufA = start, bufB = cursor
  __syncthreads();
  for (int e = t; e < EPG; e += 1024) {
    const int sl = esrc[ebase + e] - gbase;
    const int dl = edst[ebase + e] - gbase;
    const unsigned int pos = atomicAdd(&bufB[dl], 1u);
    csr[pos] = (unsigned short)sl;
  }
  __syncthreads();
  const int lane = t & 63, w = t >> 6;            // 16 waves, lane = feature
  const float* __restrict__ zlane = zr + (size_t)gbase * 64 + lane;
  float psum = 0.f;
  for (int nd = w; nd < 512; nd += 16) {
    const unsigned int s = bufA[nd], d = hist[nd];
    float a0 = 0.f, a1 = 0.f, a2 = 0.f, a3 = 0.f;
    unsigned int j = 0;
    for (; j + 4 <= d; j += 4) {                  // 4 independent loads in flight
      const int i0 = csr[s+j], i1 = csr[s+j+1], i2 = csr[s+j+2], i3 = csr[s+j+3];
      const float v0 = zlane[(size_t)i0 * 64];
      const float v1 = zlane[(size_t)i1 * 64];
      const float v2 = zlane[(size_t)i2 * 64];
      const float v3 = zlane[(size_t)i3 * 64];
      a0 += v0; a1 += v1; a2 += v2; a3 += v3;
    }
    for (; j < d; ++j) a0 += zlane[(size_t)csr[s+j] * 64];
    const float acc = (a0 + a1) + (a2 + a3);
    float v = acc / (float)(d > 0 ? d : 1) + xlb[(size_t)(gbase + nd)*64 + lane];
    v = fmaxf(v, 0.f);
    xout[(size_t)(gbase + nd)*64 + lane] = v;
    psum += v;
  }
  red[w][lane] = psum;
  __syncthreads();
  if (t < 64) {
    float s = 0.f;
    #pragma unroll
    for (int ww = 0; ww < 16; ++ww) s += red[ww][t];
    g_xs[g*384 + xs_off + t] = s * (1.f/512.f);
  }
}

// ============================================================================
// Small (n=57 or 7) aggregation over compacted edges + fused gmp.
// ============================================================================
template<int NPER>
__global__ __launch_bounds__(256)
void agg_small(int zr_idx, int xl_idx, int stage, int out_idx, int xs_off)
{
  __shared__ unsigned int hist[NPER], sstart[NPER], scur[NPER];
  __shared__ unsigned short csr[EPG];
  __shared__ float red[4][64];
  const float* __restrict__ zr  = g_feat[zr_idx];
  const float* __restrict__ xlb = g_feat[xl_idx];
  float* __restrict__ xout = g_feat[out_idx];
  const int* __restrict__ esrc = g_esrc[stage];
  const int* __restrict__ edst = g_edst[stage];
  const int g = blockIdx.x, t = threadIdx.x;
  const int gbase = g * NPER, ebase = g * EPG;
  const int m = g_ecnt[stage][g];
  if (t < NPER) hist[t] = 0;
  __syncthreads();
  for (int e = t; e < m; e += 256)
    atomicAdd(&hist[edst[ebase + e] - gbase], 1u);
  __syncthreads();
  if (t == 0) {
    unsigned int run = 0;
    for (int i = 0; i < NPER; ++i) { sstart[i] = run; scur[i] = run; run += hist[i]; }
  }
  __syncthreads();
  for (int e = t; e < m; e += 256) {
    const int sl = esrc[ebase + e] - gbase;
    const int dl = edst[ebase + e] - gbase;
    const unsigned int pos = atomicAdd(&scur[dl], 1u);
    csr[pos] = (unsigned short)sl;
  }
  __syncthreads();
  const int lane = t & 63, w = t >> 6;            // 4 waves
  const float* __restrict__ zlane = zr + (size_t)gbase * 64 + lane;
  float psum = 0.f;
  for (int nd = w; nd < NPER; nd += 4) {
    const unsigned int s = sstart[nd], d = hist[nd];
    float a0 = 0.f, a1 = 0.f, a2 = 0.f, a3 = 0.f;
    unsigned int j = 0;
    for (; j + 4 <= d; j += 4) {
      const int i0 = csr[s+j], i1 = csr[s+j+1], i2 = csr[s+j+2], i3 = csr[s+j+3];
      const float v0 = zlane[(size_t)i0 * 64];
      const float v1 = zlane[(size_t)i1 * 64];
      const float v2 = zlane[(size_t)i2 * 64];
      const float v3 = zlane[(size_t)i3 * 64];
      a0 += v0; a1 += v1; a2 += v2; a3 += v3;
    }
    for (; j < d; ++j) a0 += zlane[(size_t)csr[s+j] * 64];
    const float acc = (a0 + a1) + (a2 + a3);
    float v = acc / (float)(d > 0 ? d : 1) + xlb[(size_t)(gbase + nd)*64 + lane];
    v = fmaxf(v, 0.f);
    xout[(size_t)(gbase + nd)*64 + lane] = v;
    psum += v;
  }
  red[w][lane] = psum;
  __syncthreads();
  if (t < 64) {
    float s = red[0][t] + red[1][t] + red[2][t] + red[3][t];
    g_xs[g*384 + xs_off + t] = s * (1.f/(float)NPER);
  }
}

// ============================================================================
// SAG pool: score (scalar gconv via linearity) -> per-graph top-k (bitonic on
// packed (ordered-float, ~idx) keys == jax.lax.top_k semantics) ->
// new_x = x[perm]*tanh(score[perm]) -> edge compaction with remapped ids.
// ============================================================================
template<int NPER, int NPOW2, int KSEL>
__global__ __launch_bounds__(512)
void sag_pool(int in_idx,
              const int* __restrict__ esrc_ext, const int* __restrict__ edst_ext,
              int in_stage,
              const float* __restrict__ wr, const float* __restrict__ wl,
              const float* __restrict__ pb,
              int xnew_idx, int out_stage)
{
  __shared__ float zs[NPER], swl[NPER], sagg[NPER], sdeg[NPER], sscore[NPER];
  __shared__ unsigned long long keys[NPOW2];
  __shared__ short newpos[NPER];
  __shared__ int scnt;
  const float* __restrict__ xin = g_feat[in_idx];
  float* __restrict__ xnew = g_feat[xnew_idx];
  const int* __restrict__ esrc = (in_stage < 0) ? esrc_ext : g_esrc[in_stage];
  const int* __restrict__ edst = (in_stage < 0) ? edst_ext : g_edst[in_stage];
  int* __restrict__ eosrc = g_esrc[out_stage];
  int* __restrict__ eodst = g_edst[out_stage];
  const int g = blockIdx.x, t = threadIdx.x;
  const int gbase = g * NPER, ebase = g * EPG;
  const int m = (in_stage < 0) ? EPG : g_ecnt[in_stage][g];
  const int lane = t & 63, w = t >> 6;            // 8 waves
  const float wrv = wr[lane], wlv = wl[lane];
  for (int nd = w; nd < NPER; nd += 8) {          // per-node dots via shfl reduce
    const float v = xin[(size_t)(gbase + nd)*64 + lane];
    float a = v * wrv, b = v * wlv;
    #pragma unroll
    for (int off = 32; off > 0; off >>= 1) {
      a += __shfl_xor(a, off);
      b += __shfl_xor(b, off);
    }
    if (lane == 0) { zs[nd] = a; swl[nd] = b; }
  }
  if (t < NPER) { sagg[t] = 0.f; sdeg[t] = 0.f; }
  if (t == 0) scnt = 0;
  __syncthreads();
  for (int e = t; e < m; e += 512) {              // scalar message aggregation
    const int sl = esrc[ebase + e] - gbase;
    const int dl = edst[ebase + e] - gbase;
    atomicAdd(&sagg[dl], zs[sl]);
    atomicAdd(&sdeg[dl], 1.f);
  }
  __syncthreads();
  if (t < NPER)
    sscore[t] = sagg[t] / fmaxf(sdeg[t], 1.f) + pb[0] + swl[t];
  __syncthreads();
  if (t < NPOW2) {                                // pack sort keys
    unsigned long long key = 0ull;
    if (t < NPER) {
      unsigned int u = __float_as_uint(sscore[t]);
      u = (u & 0x80000000u) ? ~u : (u | 0x80000000u);   // order-preserving map
      key = ((unsigned long long)u << 32) | (unsigned int)(~(unsigned int)t);
    }
    keys[t] = key;
  }
  __syncthreads();
  for (int kk = 2; kk <= NPOW2; kk <<= 1) {       // bitonic sort, descending
    for (int j = kk >> 1; j > 0; j >>= 1) {
      if (t < NPOW2) {
        const int ixj = t ^ j;
        if (ixj > t) {
          const unsigned long long a = keys[t], bk = keys[ixj];
          const bool up = ((t & kk) == 0);
          if (up ? (a < bk) : (a > bk)) { keys[t] = bk; keys[ixj] = a; }
        }
      }
      __syncthreads();
    }
  }
  if (t < NPER) newpos[t] = -1;
  __syncthreads();
  if (t < KSEL)
    newpos[(int)(~(unsigned int)(keys[t] & 0xffffffffull))] = (short)t;
  __syncthreads();
  for (int r = w; r < KSEL; r += 8) {             // gather selected nodes
    const int old = (int)(~(unsigned int)(keys[r] & 0xffffffffull));
    const float sc = tanhf(sscore[old]);
    xnew[(size_t)(g*KSEL + r)*64 + lane] =
        xin[(size_t)(gbase + old)*64 + lane] * sc;
  }
  for (int e = t; e < m; e += 512) {              // compact surviving edges
    const int sl = esrc[ebase + e] - gbase;
    const int dl = edst[ebase + e] - gbase;
    const int ns = newpos[sl], nd2 = newpos[dl];
    if (ns >= 0 && nd2 >= 0) {
      const int slot = atomicAdd(&scnt, 1);
      eosrc[ebase + slot] = g*KSEL + ns;
      eodst[ebase + slot] = g*KSEL + nd2;
    }
  }
  __syncthreads();
  if (t == 0) g_ecnt[out_stage][g] = scnt;
}

// ============================================================================
// MLP head: h=[B,384] -> relu(h@W1+b1) -> @W2+b2 -> log_softmax
// ============================================================================
__global__ __launch_bounds__(64)
void head(const float* __restrict__ W1, const float* __restrict__ b1,
          const float* __restrict__ W2, const float* __restrict__ b2,
          float* __restrict__ out)
{
  __shared__ float h[384], o1[64], lg[2];
  const int g = blockIdx.x, t = threadIdx.x;
  for (int i = t; i < 384; i += 64) h[i] = g_xs[g*384 + i];
  __syncthreads();
  float acc = b1[t];
  for (int j = 0; j < 384; ++j) acc += h[j] * W1[j*64 + t];
  o1[t] = fmaxf(acc, 0.f);
  __syncthreads();
  if (t < 2) {
    float a2 = b2[t];
    for (int f2 = 0; f2 < 64; ++f2) a2 += o1[f2] * W2[f2*2 + t];
    lg[t] = a2;
  }
  __syncthreads();
  if (t < 2) {
    const float mx = fmaxf(lg[0], lg[1]);
    const float lse = mx + logf(expf(lg[0]-mx) + expf(lg[1]-mx));
    out[g*2 + t] = lg[t] - lse;
  }
}

// ============================================================================
extern "C" void kernel_launch(void* const* d_in, const int* in_sizes, int n_in,
                              void* d_out, int out_size, void* d_ws, size_t ws_size,
                              hipStream_t stream)
{
  (void)in_sizes; (void)n_in; (void)d_ws; (void)ws_size; (void)out_size;
  const float* x    = (const float*)d_in[0];
  const int*   ei   = (const int*)d_in[1];
  const float* c1Wr = (const float*)d_in[2];
  const float* c1Wl = (const float*)d_in[3];
  const float* c1b  = (const float*)d_in[4];
  const float* cWr  = (const float*)d_in[5];
  const float* cWl  = (const float*)d_in[6];
  const float* cb   = (const float*)d_in[7];
  const float* pWr  = (const float*)d_in[8];
  const float* pWl  = (const float*)d_in[9];
  const float* pb   = (const float*)d_in[10];
  const float* l1W  = (const float*)d_in[11];
  const float* l1b  = (const float*)d_in[12];
  const float* l2W  = (const float*)d_in[13];
  const float* l2b  = (const float*)d_in[14];
  float* out = (float*)d_out;
  const int* esrc = ei;
  const int* edst = ei + ETOT;

  // conv1 (160->64) + relu, xs[0]
  mm_dual<160><<<NN0/128, 256, 0, stream>>>(x, -1, c1Wr, c1Wl, c1b, 0, 1);
  agg_full<<<NB, 1024, 0, stream>>>(0, 1, esrc, edst, 1, 0);
  // convs[0] + relu, xs[1]
  mm_dual<64><<<NN0/128, 256, 0, stream>>>(nullptr, 1, cWr, cWl, cb, 0, 2);
  agg_full<<<NB, 1024, 0, stream>>>(0, 2, esrc, edst, 2, 64);
  // pool0: 512 -> 57
  sag_pool<512,512,57><<<NB, 512, 0, stream>>>(2, esrc, edst, -1, pWr, pWl, pb, 0, 0);
  // convs[1] + relu, xs[2]   (14592 rows = 114*128)
  mm_dual<64><<<114, 256, 0, stream>>>(nullptr, 0, cWr+4096, cWl+4096, cb+64, 1, 2);
  agg_small<57><<<NB, 256, 0, stream>>>(1, 2, 0, 2, 128);
  // convs[2] + relu, xs[3]
  mm_dual<64><<<114, 256, 0, stream>>>(nullptr, 2, cWr+8192, cWl+8192, cb+128, 1, 0);
  agg_small<57><<<NB, 256, 0, stream>>>(1, 0, 0, 0, 192);
  // pool1: 57 -> 7
  sag_pool<57,64,7><<<NB, 512, 0, stream>>>(0, nullptr, nullptr, 0, pWr+64, pWl+64, pb+1, 1, 1);
  // convs[3] + relu, xs[4]   (1792 rows = 14*128)
  mm_dual<64><<<14, 256, 0, stream>>>(nullptr, 1, cWr+12288, cWl+12288, cb+192, 0, 2);
  agg_small<7><<<NB, 256, 0, stream>>>(0, 2, 1, 2, 256);
  // convs[4] + relu, xs[5]
  mm_dual<64><<<14, 256, 0, stream>>>(nullptr, 2, cWr+16384, cWl+16384, cb+256, 0, 1);
  agg_small<7><<<NB, 256, 0, stream>>>(0, 1, 1, 1, 320);
  // head
  head<<<NB, 64, 0, stream>>>(l1W, l1b, l2W, l2b, out);
}

// Round 9
// 504.085 us; speedup vs baseline: 3.2096x; 3.2096x over previous
//
#include <hip/hip_runtime.h>
#include <math.h>

namespace {
constexpr int NB   = 256;          // graphs
constexpr int EPG  = 8192;         // edges per graph
constexpr int ETOT = NB * EPG;     // 2,097,152
constexpr int FH   = 64;           // hidden dim
constexpr int NN0  = NB * 512;     // 131072 nodes at full size
}

// ---- scratch (device globals: write-before-read each call, deterministic) ----
__device__ float g_feat[3][(size_t)NN0 * FH];   // rotating node-feature buffers
__device__ float g_xs[NB * 6 * FH];             // jumping-knowledge concat
__device__ int   g_esrc[2][ETOT];               // compacted edges (stage 0/1)
__device__ int   g_edst[2][ETOT];
__device__ int   g_ecnt[2][NB];

// ============================================================================
// Dual matmul: zr = x@Wr ; xl = x@Wl + b   (x: [M,K], W: [K,64], M % 128 == 0)
// v4: x AND weight-chunk staged via global_load_lds; k4 loop NOT unrolled
// (v3 post-mortem: unroll -> 256 VGPR -> scratch spill -> 6x regression).
// ============================================================================
template<int K>
__global__ __launch_bounds__(256)
void mm_dual(const float* __restrict__ xext, int in_idx,
             const float* __restrict__ Wr, const float* __restrict__ Wl,
             const float* __restrict__ bias, int zr_idx, int xl_idx)
{
  constexpr int RPB = 128;          // rows per block
  constexpr int KC  = 32;           // k-chunk staged in LDS
  __shared__ float xs[RPB][KC];     // 16 KB
  __shared__ float wr_s[KC][64];    // 8 KB
  __shared__ float wl_s[KC][64];    // 8 KB
  const float* __restrict__ x = (in_idx < 0) ? xext : g_feat[in_idx];
  float* __restrict__ zr = g_feat[zr_idx];
  float* __restrict__ xl = g_feat[xl_idx];
  const int t = threadIdx.x;
  const int rowbase = blockIdx.x * RPB;
  const int f  = t & 31;            // this thread's column pair: f, f+32
  const int rg = t >> 5;            // 8 row-groups x 16 rows
  const int wv = t >> 6;            // wave id (0..3)
  float ar0[16], ar1[16], al0[16], al1[16];
  #pragma unroll
  for (int r = 0; r < 16; ++r) { ar0[r]=0.f; ar1[r]=0.f; al0[r]=0.f; al1[r]=0.f; }

  for (int c = 0; c < K / KC; ++c) {
    __syncthreads();                       // WAR: previous chunk fully consumed
    #pragma unroll
    for (int i = 0; i < 4; ++i) {          // x: 1024 slots of 16B = 16 KB
      const int idx = t + i * 256;
      const int r = idx >> 3, q = idx & 7;
      const float* gp = &x[(size_t)(rowbase + r) * K + c * KC + q * 4];
      float* lp = &xs[0][0] + (size_t)(i * 256 + wv * 64) * 4;
      __builtin_amdgcn_global_load_lds(
          (const __attribute__((address_space(1))) unsigned int*)gp,
          (__attribute__((address_space(3))) unsigned int*)lp, 16, 0, 0);
    }
    const float* wsrc_r = Wr + (size_t)c * KC * 64;   // contiguous 2048 floats
    const float* wsrc_l = Wl + (size_t)c * KC * 64;
    #pragma unroll
    for (int i = 0; i < 2; ++i) {          // each W: 512 slots of 16B = 8 KB
      const int idx = t + i * 256;
      {
        const float* gp = wsrc_r + (size_t)idx * 4;
        float* lp = &wr_s[0][0] + (size_t)(i * 256 + wv * 64) * 4;
        __builtin_amdgcn_global_load_lds(
            (const __attribute__((address_space(1))) unsigned int*)gp,
            (__attribute__((address_space(3))) unsigned int*)lp, 16, 0, 0);
      }
      {
        const float* gp = wsrc_l + (size_t)idx * 4;
        float* lp = &wl_s[0][0] + (size_t)(i * 256 + wv * 64) * 4;
        __builtin_amdgcn_global_load_lds(
            (const __attribute__((address_space(1))) unsigned int*)gp,
            (__attribute__((address_space(3))) unsigned int*)lp, 16, 0, 0);
      }
    }
    __syncthreads();                       // drains vmcnt: LDS writes visible
    for (int k4 = 0; k4 < KC / 4; ++k4) {  // NOT unrolled (register budget)
      const int kb = k4 * 4;
      const float wr00=wr_s[kb+0][f],    wr01=wr_s[kb+1][f],
                  wr02=wr_s[kb+2][f],    wr03=wr_s[kb+3][f];
      const float wr10=wr_s[kb+0][f+32], wr11=wr_s[kb+1][f+32],
                  wr12=wr_s[kb+2][f+32], wr13=wr_s[kb+3][f+32];
      const float wl00=wl_s[kb+0][f],    wl01=wl_s[kb+1][f],
                  wl02=wl_s[kb+2][f],    wl03=wl_s[kb+3][f];
      const float wl10=wl_s[kb+0][f+32], wl11=wl_s[kb+1][f+32],
                  wl12=wl_s[kb+2][f+32], wl13=wl_s[kb+3][f+32];
      #pragma unroll
      for (int r = 0; r < 16; ++r) {
        const float4 xv = *reinterpret_cast<const float4*>(&xs[rg*16 + r][kb]);
        ar0[r] += xv.x*wr00 + xv.y*wr01 + xv.z*wr02 + xv.w*wr03;
        ar1[r] += xv.x*wr10 + xv.y*wr11 + xv.z*wr12 + xv.w*wr13;
        al0[r] += xv.x*wl00 + xv.y*wl01 + xv.z*wl02 + xv.w*wl03;
        al1[r] += xv.x*wl10 + xv.y*wl11 + xv.z*wl12 + xv.w*wl13;
      }
    }
  }
  const float bv0 = bias[f], bv1 = bias[f + 32];
  #pragma unroll
  for (int r = 0; r < 16; ++r) {
    const size_t row = (size_t)(rowbase + rg * 16 + r);
    zr[row * 64 + f]      = ar0[r];
    zr[row * 64 + f + 32] = ar1[r];
    xl[row * 64 + f]      = al0[r] + bv0;
    xl[row * 64 + f + 32] = al1[r] + bv1;
  }
}

// ============================================================================
// Full-size (n=512/graph) mean-aggregation + residual + relu + fused gmp.
// v3: gather unrolled x4 with independent accumulators (hide L2 latency).
// ============================================================================
__global__ __launch_bounds__(1024)
void agg_full(int zr_idx, int xl_idx,
              const int* __restrict__ esrc, const int* __restrict__ edst,
              int out_idx, int xs_off)
{
  __shared__ unsigned int hist[512], bufA[512], bufB[512];
  __shared__ unsigned short csr[EPG];
  __shared__ float red[16][64];
  const float* __restrict__ zr  = g_feat[zr_idx];
  const float* __restrict__ xlb = g_feat[xl_idx];
  float* __restrict__ xout = g_feat[out_idx];
  const int g = blockIdx.x, t = threadIdx.x;
  const int gbase = g * 512, ebase = g * EPG;
  for (int i = t; i < 512; i += 1024) hist[i] = 0;
  __syncthreads();
  for (int e = t; e < EPG; e += 1024)
    atomicAdd(&hist[edst[ebase + e] - gbase], 1u);
  __syncthreads();
  if (t < 512) bufA[t] = hist[t];
  __syncthreads();
  unsigned int *pa = bufA, *pb = bufB;
  for (int off = 1; off < 512; off <<= 1) {      // Hillis-Steele inclusive scan
    if (t < 512) {
      unsigned int v = pa[t];
      if (t >= off) v += pa[t - off];
      pb[t] = v;
    }
    __syncthreads();
    unsigned int* tmp = pa; pa = pb; pb = tmp;
  }
  unsigned int excl = 0;
  if (t < 512) excl = pa[t] - hist[t];
  __syncthreads();
  if (t < 512) { bufA[t] = excl; bufB[t] = excl; }  // bufA = start, bufB = cursor
  __syncthreads();
  for (int e = t; e < EPG; e += 1024) {
    const int sl = esrc[ebase + e] - gbase;
    const int dl = edst[ebase + e] - gbase;
    const unsigned int pos = atomicAdd(&bufB[dl], 1u);
    csr[pos] = (unsigned short)sl;
  }
  __syncthreads();
  const int lane = t & 63, w = t >> 6;            // 16 waves, lane = feature
  const float* __restrict__ zlane = zr + (size_t)gbase * 64 + lane;
  float psum = 0.f;
  for (int nd = w; nd < 512; nd += 16) {
    const unsigned int s = bufA[nd], d = hist[nd];
    float a0 = 0.f, a1 = 0.f, a2 = 0.f, a3 = 0.f;
    unsigned int j = 0;
    for (; j + 4 <= d; j += 4) {                  // 4 independent loads in flight
      const int i0 = csr[s+j], i1 = csr[s+j+1], i2 = csr[s+j+2], i3 = csr[s+j+3];
      const float v0 = zlane[(size_t)i0 * 64];
      const float v1 = zlane[(size_t)i1 * 64];
      const float v2 = zlane[(size_t)i2 * 64];
      const float v3 = zlane[(size_t)i3 * 64];
      a0 += v0; a1 += v1; a2 += v2; a3 += v3;
    }
    for (; j < d; ++j) a0 += zlane[(size_t)csr[s+j] * 64];
    const float acc = (a0 + a1) + (a2 + a3);
    float v = acc / (float)(d > 0 ? d : 1) + xlb[(size_t)(gbase + nd)*64 + lane];
    v = fmaxf(v, 0.f);
    xout[(size_t)(gbase + nd)*64 + lane] = v;
    psum += v;
  }
  red[w][lane] = psum;
  __syncthreads();
  if (t < 64) {
    float s = 0.f;
    #pragma unroll
    for (int ww = 0; ww < 16; ++ww) s += red[ww][t];
    g_xs[g*384 + xs_off + t] = s * (1.f/512.f);
  }
}

// ============================================================================
// Small (n=57 or 7) aggregation over compacted edges + fused gmp.
// ============================================================================
template<int NPER>
__global__ __launch_bounds__(256)
void agg_small(int zr_idx, int xl_idx, int stage, int out_idx, int xs_off)
{
  __shared__ unsigned int hist[NPER], sstart[NPER], scur[NPER];
  __shared__ unsigned short csr[EPG];
  __shared__ float red[4][64];
  const float* __restrict__ zr  = g_feat[zr_idx];
  const float* __restrict__ xlb = g_feat[xl_idx];
  float* __restrict__ xout = g_feat[out_idx];
  const int* __restrict__ esrc = g_esrc[stage];
  const int* __restrict__ edst = g_edst[stage];
  const int g = blockIdx.x, t = threadIdx.x;
  const int gbase = g * NPER, ebase = g * EPG;
  const int m = g_ecnt[stage][g];
  if (t < NPER) hist[t] = 0;
  __syncthreads();
  for (int e = t; e < m; e += 256)
    atomicAdd(&hist[edst[ebase + e] - gbase], 1u);
  __syncthreads();
  if (t == 0) {
    unsigned int run = 0;
    for (int i = 0; i < NPER; ++i) { sstart[i] = run; scur[i] = run; run += hist[i]; }
  }
  __syncthreads();
  for (int e = t; e < m; e += 256) {
    const int sl = esrc[ebase + e] - gbase;
    const int dl = edst[ebase + e] - gbase;
    const unsigned int pos = atomicAdd(&scur[dl], 1u);
    csr[pos] = (unsigned short)sl;
  }
  __syncthreads();
  const int lane = t & 63, w = t >> 6;            // 4 waves
  const float* __restrict__ zlane = zr + (size_t)gbase * 64 + lane;
  float psum = 0.f;
  for (int nd = w; nd < NPER; nd += 4) {
    const unsigned int s = sstart[nd], d = hist[nd];
    float a0 = 0.f, a1 = 0.f, a2 = 0.f, a3 = 0.f;
    unsigned int j = 0;
    for (; j + 4 <= d; j += 4) {
      const int i0 = csr[s+j], i1 = csr[s+j+1], i2 = csr[s+j+2], i3 = csr[s+j+3];
      const float v0 = zlane[(size_t)i0 * 64];
      const float v1 = zlane[(size_t)i1 * 64];
      const float v2 = zlane[(size_t)i2 * 64];
      const float v3 = zlane[(size_t)i3 * 64];
      a0 += v0; a1 += v1; a2 += v2; a3 += v3;
    }
    for (; j < d; ++j) a0 += zlane[(size_t)csr[s+j] * 64];
    const float acc = (a0 + a1) + (a2 + a3);
    float v = acc / (float)(d > 0 ? d : 1) + xlb[(size_t)(gbase + nd)*64 + lane];
    v = fmaxf(v, 0.f);
    xout[(size_t)(gbase + nd)*64 + lane] = v;
    psum += v;
  }
  red[w][lane] = psum;
  __syncthreads();
  if (t < 64) {
    float s = red[0][t] + red[1][t] + red[2][t] + red[3][t];
    g_xs[g*384 + xs_off + t] = s * (1.f/(float)NPER);
  }
}

// ============================================================================
// SAG pool: score (scalar gconv via linearity) -> per-graph top-k (bitonic on
// packed (ordered-float, ~idx) keys == jax.lax.top_k semantics) ->
// new_x = x[perm]*tanh(score[perm]) -> edge compaction with remapped ids.
// ============================================================================
template<int NPER, int NPOW2, int KSEL>
__global__ __launch_bounds__(512)
void sag_pool(int in_idx,
              const int* __restrict__ esrc_ext, const int* __restrict__ edst_ext,
              int in_stage,
              const float* __restrict__ wr, const float* __restrict__ wl,
              const float* __restrict__ pb,
              int xnew_idx, int out_stage)
{
  __shared__ float zs[NPER], swl[NPER], sagg[NPER], sdeg[NPER], sscore[NPER];
  __shared__ unsigned long long keys[NPOW2];
  __shared__ short newpos[NPER];
  __shared__ int scnt;
  const float* __restrict__ xin = g_feat[in_idx];
  float* __restrict__ xnew = g_feat[xnew_idx];
  const int* __restrict__ esrc = (in_stage < 0) ? esrc_ext : g_esrc[in_stage];
  const int* __restrict__ edst = (in_stage < 0) ? edst_ext : g_edst[in_stage];
  int* __restrict__ eosrc = g_esrc[out_stage];
  int* __restrict__ eodst = g_edst[out_stage];
  const int g = blockIdx.x, t = threadIdx.x;
  const int gbase = g * NPER, ebase = g * EPG;
  const int m = (in_stage < 0) ? EPG : g_ecnt[in_stage][g];
  const int lane = t & 63, w = t >> 6;            // 8 waves
  const float wrv = wr[lane], wlv = wl[lane];
  for (int nd = w; nd < NPER; nd += 8) {          // per-node dots via shfl reduce
    const float v = xin[(size_t)(gbase + nd)*64 + lane];
    float a = v * wrv, b = v * wlv;
    #pragma unroll
    for (int off = 32; off > 0; off >>= 1) {
      a += __shfl_xor(a, off);
      b += __shfl_xor(b, off);
    }
    if (lane == 0) { zs[nd] = a; swl[nd] = b; }
  }
  if (t < NPER) { sagg[t] = 0.f; sdeg[t] = 0.f; }
  if (t == 0) scnt = 0;
  __syncthreads();
  for (int e = t; e < m; e += 512) {              // scalar message aggregation
    const int sl = esrc[ebase + e] - gbase;
    const int dl = edst[ebase + e] - gbase;
    atomicAdd(&sagg[dl], zs[sl]);
    atomicAdd(&sdeg[dl], 1.f);
  }
  __syncthreads();
  if (t < NPER)
    sscore[t] = sagg[t] / fmaxf(sdeg[t], 1.f) + pb[0] + swl[t];
  __syncthreads();
  if (t < NPOW2) {                                // pack sort keys
    unsigned long long key = 0ull;
    if (t < NPER) {
      unsigned int u = __float_as_uint(sscore[t]);
      u = (u & 0x80000000u) ? ~u : (u | 0x80000000u);   // order-preserving map
      key = ((unsigned long long)u << 32) | (unsigned int)(~(unsigned int)t);
    }
    keys[t] = key;
  }
  __syncthreads();
  for (int kk = 2; kk <= NPOW2; kk <<= 1) {       // bitonic sort, descending
    for (int j = kk >> 1; j > 0; j >>= 1) {
      if (t < NPOW2) {
        const int ixj = t ^ j;
        if (ixj > t) {
          const unsigned long long a = keys[t], bk = keys[ixj];
          const bool up = ((t & kk) == 0);
          if (up ? (a < bk) : (a > bk)) { keys[t] = bk; keys[ixj] = a; }
        }
      }
      __syncthreads();
    }
  }
  if (t < NPER) newpos[t] = -1;
  __syncthreads();
  if (t < KSEL)
    newpos[(int)(~(unsigned int)(keys[t] & 0xffffffffull))] = (short)t;
  __syncthreads();
  for (int r = w; r < KSEL; r += 8) {             // gather selected nodes
    const int old = (int)(~(unsigned int)(keys[r] & 0xffffffffull));
    const float sc = tanhf(sscore[old]);
    xnew[(size_t)(g*KSEL + r)*64 + lane] =
        xin[(size_t)(gbase + old)*64 + lane] * sc;
  }
  for (int e = t; e < m; e += 512) {              // compact surviving edges
    const int sl = esrc[ebase + e] - gbase;
    const int dl = edst[ebase + e] - gbase;
    const int ns = newpos[sl], nd2 = newpos[dl];
    if (ns >= 0 && nd2 >= 0) {
      const int slot = atomicAdd(&scnt, 1);
      eosrc[ebase + slot] = g*KSEL + ns;
      eodst[ebase + slot] = g*KSEL + nd2;
    }
  }
  __syncthreads();
  if (t == 0) g_ecnt[out_stage][g] = scnt;
}

// ============================================================================
// MLP head: h=[B,384] -> relu(h@W1+b1) -> @W2+b2 -> log_softmax
// ============================================================================
__global__ __launch_bounds__(64)
void head(const float* __restrict__ W1, const float* __restrict__ b1,
          const float* __restrict__ W2, const float* __restrict__ b2,
          float* __restrict__ out)
{
  __shared__ float h[384], o1[64], lg[2];
  const int g = blockIdx.x, t = threadIdx.x;
  for (int i = t; i < 384; i += 64) h[i] = g_xs[g*384 + i];
  __syncthreads();
  float acc = b1[t];
  for (int j = 0; j < 384; ++j) acc += h[j] * W1[j*64 + t];
  o1[t] = fmaxf(acc, 0.f);
  __syncthreads();
  if (t < 2) {
    float a2 = b2[t];
    for (int f2 = 0; f2 < 64; ++f2) a2 += o1[f2] * W2[f2*2 + t];
    lg[t] = a2;
  }
  __syncthreads();
  if (t < 2) {
    const float mx = fmaxf(lg[0], lg[1]);
    const float lse = mx + logf(expf(lg[0]-mx) + expf(lg[1]-mx));
    out[g*2 + t] = lg[t] - lse;
  }
}

// ============================================================================
extern "C" void kernel_launch(void* const* d_in, const int* in_sizes, int n_in,
                              void* d_out, int out_size, void* d_ws, size_t ws_size,
                              hipStream_t stream)
{
  (void)in_sizes; (void)n_in; (void)d_ws; (void)ws_size; (void)out_size;
  const float* x    = (const float*)d_in[0];
  const int*   ei   = (const int*)d_in[1];
  const float* c1Wr = (const float*)d_in[2];
  const float* c1Wl = (const float*)d_in[3];
  const float* c1b  = (const float*)d_in[4];
  const float* cWr  = (const float*)d_in[5];
  const float* cWl  = (const float*)d_in[6];
  const float* cb   = (const float*)d_in[7];
  const float* pWr  = (const float*)d_in[8];
  const float* pWl  = (const float*)d_in[9];
  const float* pb   = (const float*)d_in[10];
  const float* l1W  = (const float*)d_in[11];
  const float* l1b  = (const float*)d_in[12];
  const float* l2W  = (const float*)d_in[13];
  const float* l2b  = (const float*)d_in[14];
  float* out = (float*)d_out;
  const int* esrc = ei;
  const int* edst = ei + ETOT;

  // conv1 (160->64) + relu, xs[0]
  mm_dual<160><<<NN0/128, 256, 0, stream>>>(x, -1, c1Wr, c1Wl, c1b, 0, 1);
  agg_full<<<NB, 1024, 0, stream>>>(0, 1, esrc, edst, 1, 0);
  // convs[0] + relu, xs[1]
  mm_dual<64><<<NN0/128, 256, 0, stream>>>(nullptr, 1, cWr, cWl, cb, 0, 2);
  agg_full<<<NB, 1024, 0, stream>>>(0, 2, esrc, edst, 2, 64);
  // pool0: 512 -> 57
  sag_pool<512,512,57><<<NB, 512, 0, stream>>>(2, esrc, edst, -1, pWr, pWl, pb, 0, 0);
  // convs[1] + relu, xs[2]   (14592 rows = 114*128)
  mm_dual<64><<<114, 256, 0, stream>>>(nullptr, 0, cWr+4096, cWl+4096, cb+64, 1, 2);
  agg_small<57><<<NB, 256, 0, stream>>>(1, 2, 0, 2, 128);
  // convs[2] + relu, xs[3]
  mm_dual<64><<<114, 256, 0, stream>>>(nullptr, 2, cWr+8192, cWl+8192, cb+128, 1, 0);
  agg_small<57><<<NB, 256, 0, stream>>>(1, 0, 0, 0, 192);
  // pool1: 57 -> 7
  sag_pool<57,64,7><<<NB, 512, 0, stream>>>(0, nullptr, nullptr, 0, pWr+64, pWl+64, pb+1, 1, 1);
  // convs[3] + relu, xs[4]   (1792 rows = 14*128)
  mm_dual<64><<<14, 256, 0, stream>>>(nullptr, 1, cWr+12288, cWl+12288, cb+192, 0, 2);
  agg_small<7><<<NB, 256, 0, stream>>>(0, 2, 1, 2, 256);
  // convs[4] + relu, xs[5]
  mm_dual<64><<<14, 256, 0, stream>>>(nullptr, 2, cWr+16384, cWl+16384, cb+256, 0, 1);
  agg_small<7><<<NB, 256, 0, stream>>>(0, 1, 1, 1, 320);
  // head
  head<<<NB, 64, 0, stream>>>(l1W, l1b, l2W, l2b, out);
}